// Round 6
// baseline (794.691 us; speedup 1.0000x reference)
//
#include <hip/hip_runtime.h>
#include <hip/hip_bf16.h>

// Problem constants
#define BB   8
#define NN   1024
#define CC   768
#define HH   12
#define DD   64
#define HIDN 3072
#define MROWS 16384   // 2*B*N
#define HALFM 8192

typedef __attribute__((ext_vector_type(8))) short bf16x8;
typedef __attribute__((ext_vector_type(4))) float f32x4;

__device__ __forceinline__ void gload16(const void* g, void* l) {
  __builtin_amdgcn_global_load_lds((const __attribute__((address_space(1))) void*)g,
                                   (__attribute__((address_space(3))) void*)l, 16, 0, 0);
}

__device__ __forceinline__ unsigned short f2bf(float f) {
  __hip_bfloat16 h = __float2bfloat16(f);
  return *reinterpret_cast<unsigned short*>(&h);
}

// ---------------- weight cast f32 -> bf16 (vectorized x4) ----------------
__global__ void cast_f32_bf16(const float* __restrict__ src,
                              unsigned short* __restrict__ dst, int n4) {
  int i = blockIdx.x * blockDim.x + threadIdx.x;
  if (i >= n4) return;
  float4 v = ((const float4*)src)[i];
  ushort4 o;
  o.x = f2bf(v.x); o.y = f2bf(v.y); o.z = f2bf(v.z); o.w = f2bf(v.w);
  ((ushort4*)dst)[i] = o;
}

// ---------------- LayerNorm (f32 in, bf16 out), one block per row ----------------
__global__ __launch_bounds__(256) void ln_kernel(
    const float* __restrict__ src1, const float* __restrict__ src2, int halfRows,
    const float* __restrict__ gam, const float* __restrict__ bet,
    unsigned short* __restrict__ outp) {
  int row = blockIdx.x;
  const float* src = (row < halfRows) ? (src1 + (size_t)row * CC)
                                      : (src2 + (size_t)(row - halfRows) * CC);
  int tid = threadIdx.x;
  float a0 = src[tid], a1 = src[tid + 256], a2 = src[tid + 512];
  float s = a0 + a1 + a2;
  float sq = a0 * a0 + a1 * a1 + a2 * a2;
  __shared__ float sm[8];
  for (int msk = 1; msk < 64; msk <<= 1) {
    s  += __shfl_xor(s, msk);
    sq += __shfl_xor(sq, msk);
  }
  int w = tid >> 6, l = tid & 63;
  if (l == 0) { sm[w] = s; sm[4 + w] = sq; }
  __syncthreads();
  s  = sm[0] + sm[1] + sm[2] + sm[3];
  sq = sm[4] + sm[5] + sm[6] + sm[7];
  float mu  = s * (1.0f / CC);
  float var = sq * (1.0f / CC) - mu * mu;
  float rs  = rsqrtf(var + 1e-5f);
  size_t ob = (size_t)row * CC;
  outp[ob + tid]       = f2bf((a0 - mu) * rs * gam[tid]       + bet[tid]);
  outp[ob + tid + 256] = f2bf((a1 - mu) * rs * gam[tid + 256] + bet[tid + 256]);
  outp[ob + tid + 512] = f2bf((a2 - mu) * rs * gam[tid + 512] + bet[tid + 512]);
}

// ---------------- GEMM: out[M,N] = A[M,K](bf16) @ W[N,K]^T (bf16) ----------------
// EPI 0: bf16 store, no bias (QKV)
// EPI 1: f32 store, + bias + residual (proj, fc2)
// EPI 2: bf16 store, gelu(acc + bias) (fc1)
template <int EPI>
__global__ __launch_bounds__(256) void gemm_bt(
    const unsigned short* __restrict__ A, const unsigned short* __restrict__ W,
    const float* __restrict__ bias,
    const float* __restrict__ res1, const float* __restrict__ res2,
    float* __restrict__ outF, unsigned short* __restrict__ outB,
    int M, int Nn, int K, int halfM) {
  __shared__ unsigned short As[128 * 32];
  __shared__ unsigned short Bs[128 * 32];
  int tid = threadIdx.x;
  int w = tid >> 6, l = tid & 63, lg = l >> 4, li = l & 15;
  int wr = w >> 1, wc = w & 1;
  int tN = blockIdx.x * 128, tM = blockIdx.y * 128;

  f32x4 acc[4][4];
  f32x4 zz = {0.f, 0.f, 0.f, 0.f};
#pragma unroll
  for (int i = 0; i < 4; ++i)
#pragma unroll
    for (int j = 0; j < 4; ++j) acc[i][j] = zz;

  int r4 = tid >> 2;
  int c8 = (tid & 3) * 8;
  const unsigned short* gA0 = A + (size_t)(tM + r4) * K + c8;
  const unsigned short* gA1 = A + (size_t)(tM + 64 + r4) * K + c8;
  const unsigned short* gB0 = W + (size_t)(tN + r4) * K + c8;
  const unsigned short* gB1 = W + (size_t)(tN + 64 + r4) * K + c8;
  unsigned short* lA0 = &As[(size_t)tid * 8];
  unsigned short* lA1 = &As[(size_t)(256 + tid) * 8];
  unsigned short* lB0 = &Bs[(size_t)tid * 8];
  unsigned short* lB1 = &Bs[(size_t)(256 + tid) * 8];

  int nk = K >> 5;
  for (int kt = 0; kt < nk; ++kt) {
    __syncthreads();
    int ko = kt * 32;
    gload16(gA0 + ko, lA0);
    gload16(gA1 + ko, lA1);
    gload16(gB0 + ko, lB0);
    gload16(gB1 + ko, lB1);
    __syncthreads();
    bf16x8 af[4], bq[4];
#pragma unroll
    for (int fm = 0; fm < 4; ++fm)
      af[fm] = *(const bf16x8*)&As[(wr * 64 + fm * 16 + li) * 32 + lg * 8];
#pragma unroll
    for (int fn = 0; fn < 4; ++fn)
      bq[fn] = *(const bf16x8*)&Bs[(wc * 64 + fn * 16 + li) * 32 + lg * 8];
#pragma unroll
    for (int fm = 0; fm < 4; ++fm)
#pragma unroll
      for (int fn = 0; fn < 4; ++fn)
        acc[fm][fn] = __builtin_amdgcn_mfma_f32_16x16x32_bf16(af[fm], bq[fn], acc[fm][fn], 0, 0, 0);
  }

#pragma unroll
  for (int fm = 0; fm < 4; ++fm) {
    int rowb = tM + wr * 64 + fm * 16 + lg * 4;
#pragma unroll
    for (int fn = 0; fn < 4; ++fn) {
      int col = tN + wc * 64 + fn * 16 + li;
      f32x4 v = acc[fm][fn];
#pragma unroll
      for (int rr = 0; rr < 4; ++rr) {
        int row = rowb + rr;
        size_t idx = (size_t)row * Nn + col;
        float x = v[rr];
        if (EPI == 0) {
          outB[idx] = f2bf(x);
        } else if (EPI == 1) {
          float r = (row < halfM) ? res1[(size_t)row * Nn + col]
                                  : res2[(size_t)(row - halfM) * Nn + col];
          outF[idx] = x + bias[col] + r;
        } else {
          float t = x + bias[col];
          float gl = 0.5f * t * (1.0f + erff(t * 0.70710678118654752f));
          outB[idx] = f2bf(gl);
        }
      }
    }
  }
}

// ---------------- Flash attention over qkv buffer ----------------
// qkv: [16384, 2304] bf16 rows: ch0 = rows 0..8191 (from n1), ch1 = 8192.. (from n2)
// Q always from ch0; K/V from channel blockIdx.z. out: [16384, 768] bf16.
__global__ __launch_bounds__(256) void attn_kernel(
    const unsigned short* __restrict__ qkv, unsigned short* __restrict__ outp) {
  __shared__ unsigned short Ks[64 * 72];
  __shared__ unsigned short Vt[64 * 72];
  __shared__ unsigned short Pw[4][16 * 72];
  int tid = threadIdx.x;
  int w = tid >> 6, l = tid & 63, lg = l >> 4, li = l & 15;
  int qt = blockIdx.x;
  int b = blockIdx.y / HH;
  int h = blockIdx.y % HH;
  int br = blockIdx.z;

  int qrow0  = b * NN + qt * 64;          // channel 0 rows
  int kvrow0 = br * HALFM + b * NN;
  int orow0  = br * HALFM + b * NN + qt * 64;

  bf16x8 qa[2];
  {
    size_t qr = (size_t)(qrow0 + w * 16 + li) * (3 * CC) + h * DD;
    qa[0] = *(const bf16x8*)(qkv + qr + lg * 8);
    qa[1] = *(const bf16x8*)(qkv + qr + 32 + lg * 8);
  }

  float m[4], lsum[4];
  f32x4 oacc[4];
  f32x4 zz = {0.f, 0.f, 0.f, 0.f};
#pragma unroll
  for (int r = 0; r < 4; ++r) { m[r] = -1e30f; lsum[r] = 0.f; }
#pragma unroll
  for (int fn = 0; fn < 4; ++fn) oacc[fn] = zz;

  for (int kt = 0; kt < 16; ++kt) {
    __syncthreads();
#pragma unroll
    for (int pass = 0; pass < 2; ++pass) {
      int r = (tid >> 3) + pass * 32;
      int co = (tid & 7) * 8;
      size_t grow = (size_t)(kvrow0 + kt * 64 + r) * (3 * CC) + h * DD;
      bf16x8 kv = *(const bf16x8*)(qkv + grow + CC + co);
      *(bf16x8*)&Ks[r * 72 + co] = kv;
      bf16x8 vv = *(const bf16x8*)(qkv + grow + 2 * CC + co);
#pragma unroll
      for (int j = 0; j < 8; ++j) Vt[(co + j) * 72 + r] = ((unsigned short*)&vv)[j];
    }
    __syncthreads();

    // S = Q K^T (rows: this wave's 16 q-rows; cols: 64 kv)
    f32x4 s[4];
#pragma unroll
    for (int fn = 0; fn < 4; ++fn) s[fn] = zz;
#pragma unroll
    for (int ks = 0; ks < 2; ++ks)
#pragma unroll
      for (int fn = 0; fn < 4; ++fn) {
        bf16x8 bk = *(const bf16x8*)&Ks[(fn * 16 + li) * 72 + ks * 32 + lg * 8];
        s[fn] = __builtin_amdgcn_mfma_f32_16x16x32_bf16(qa[ks], bk, s[fn], 0, 0, 0);
      }
#pragma unroll
    for (int fn = 0; fn < 4; ++fn)
#pragma unroll
      for (int r = 0; r < 4; ++r) s[fn][r] *= 0.125f;

    float p[4][4];
    float alpha[4];
#pragma unroll
    for (int r = 0; r < 4; ++r) {
      float v = fmaxf(fmaxf(s[0][r], s[1][r]), fmaxf(s[2][r], s[3][r]));
      for (int msk = 1; msk < 16; msk <<= 1) v = fmaxf(v, __shfl_xor(v, msk));
      float mn = fmaxf(m[r], v);
      float al = __expf(m[r] - mn);
      m[r] = mn;
      float srow = 0.f;
#pragma unroll
      for (int fn = 0; fn < 4; ++fn) {
        float e = __expf(s[fn][r] - mn);
        p[fn][r] = e;
        srow += e;
      }
      for (int msk = 1; msk < 16; msk <<= 1) srow += __shfl_xor(srow, msk);
      lsum[r] = lsum[r] * al + srow;
      alpha[r] = al;
    }
#pragma unroll
    for (int fn = 0; fn < 4; ++fn)
#pragma unroll
      for (int r = 0; r < 4; ++r) oacc[fn][r] *= alpha[r];

    // P -> per-wave LDS (C-layout -> A-layout reshape)
#pragma unroll
    for (int fn = 0; fn < 4; ++fn)
#pragma unroll
      for (int r = 0; r < 4; ++r)
        Pw[w][(lg * 4 + r) * 72 + fn * 16 + li] = f2bf(p[fn][r]);
    asm volatile("s_waitcnt lgkmcnt(0)" ::: "memory");

    // O += P @ V
#pragma unroll
    for (int ks = 0; ks < 2; ++ks) {
      bf16x8 pa = *(const bf16x8*)&Pw[w][li * 72 + ks * 32 + lg * 8];
#pragma unroll
      for (int fn = 0; fn < 4; ++fn) {
        bf16x8 bv = *(const bf16x8*)&Vt[(fn * 16 + li) * 72 + ks * 32 + lg * 8];
        oacc[fn] = __builtin_amdgcn_mfma_f32_16x16x32_bf16(pa, bv, oacc[fn], 0, 0, 0);
      }
    }
  }

#pragma unroll
  for (int fn = 0; fn < 4; ++fn)
#pragma unroll
    for (int r = 0; r < 4; ++r) {
      int orow = orow0 + w * 16 + lg * 4 + r;
      int ocol = h * DD + fn * 16 + li;
      outp[(size_t)orow * CC + ocol] = f2bf(oacc[fn][r] / lsum[r]);
    }
}

// ---------------- launch ----------------
extern "C" void kernel_launch(void* const* d_in, const int* in_sizes, int n_in,
                              void* d_out, int out_size, void* d_ws, size_t ws_size,
                              hipStream_t stream) {
  const float* x1     = (const float*)d_in[0];
  const float* x2     = (const float*)d_in[1];
  const float* w_qkv  = (const float*)d_in[2];
  const float* w_proj = (const float*)d_in[3];
  const float* b_proj = (const float*)d_in[4];
  const float* g1     = (const float*)d_in[5];
  const float* b1     = (const float*)d_in[6];
  const float* g2     = (const float*)d_in[7];
  const float* b2     = (const float*)d_in[8];
  const float* w_fc1  = (const float*)d_in[9];
  const float* b_fc1  = (const float*)d_in[10];
  const float* w_fc2  = (const float*)d_in[11];
  const float* b_fc2  = (const float*)d_in[12];
  float* out = (float*)d_out;

  char* ws = (char*)d_ws;
  unsigned short* wq   = (unsigned short*)(ws + 0);          //  3,538,944 B
  unsigned short* wp   = (unsigned short*)(ws + 3538944);    //  1,179,648 B
  unsigned short* wf1  = (unsigned short*)(ws + 4718592);    //  4,718,592 B
  unsigned short* wf2  = (unsigned short*)(ws + 9437184);    //  4,718,592 B
  unsigned short* bufA = (unsigned short*)(ws + 14155776);   // 25,165,824 B (n12 / attn_out / ln2)
  unsigned short* bufB = (unsigned short*)(ws + 39321600);   // 100,663,296 B (qkv / mlp hidden)

  // weights -> bf16
  cast_f32_bf16<<<(3 * CC * CC / 4 + 255) / 256, 256, 0, stream>>>(w_qkv, wq, 3 * CC * CC / 4);
  cast_f32_bf16<<<(CC * CC / 4 + 255) / 256, 256, 0, stream>>>(w_proj, wp, CC * CC / 4);
  cast_f32_bf16<<<(HIDN * CC / 4 + 255) / 256, 256, 0, stream>>>(w_fc1, wf1, HIDN * CC / 4);
  cast_f32_bf16<<<(CC * HIDN / 4 + 255) / 256, 256, 0, stream>>>(w_fc2, wf2, CC * HIDN / 4);

  // LN1(x1|x2) -> bufA bf16 [16384,768]
  ln_kernel<<<MROWS, 256, 0, stream>>>(x1, x2, HALFM, g1, b1, bufA);

  // QKV: bufA @ wq^T -> bufB bf16 [16384,2304]
  gemm_bt<0><<<dim3(18, 128), 256, 0, stream>>>(bufA, wq, nullptr, nullptr, nullptr,
                                                nullptr, bufB, MROWS, 3 * CC, CC, HALFM);

  // attention: bufB -> bufA bf16 [16384,768]
  attn_kernel<<<dim3(16, BB * HH, 2), 256, 0, stream>>>(bufB, bufA);

  // proj + bias + residual(x1|x2) -> d_out f32 [16384,768]
  gemm_bt<1><<<dim3(6, 128), 256, 0, stream>>>(bufA, wp, b_proj, x1, x2,
                                               out, nullptr, MROWS, CC, CC, HALFM);

  // LN2(d_out) -> bufA bf16
  ln_kernel<<<MROWS, 256, 0, stream>>>(out, out + (size_t)HALFM * CC, HALFM, g2, b2, bufA);

  // fc1 + bias + gelu -> bufB bf16 [16384,3072]
  gemm_bt<2><<<dim3(24, 128), 256, 0, stream>>>(bufA, wf1, b_fc1, nullptr, nullptr,
                                                nullptr, bufB, MROWS, HIDN, CC, HALFM);

  // fc2 + bias + residual(d_out) -> d_out f32
  gemm_bt<1><<<dim3(6, 128), 256, 0, stream>>>(bufB, wf2, b_fc2, out, out + (size_t)HALFM * CC,
                                               out, nullptr, MROWS, CC, HIDN, HALFM);
}

// Round 9
// 762.139 us; speedup vs baseline: 1.0427x; 1.0427x over previous
//
#include <hip/hip_runtime.h>
#include <hip/hip_bf16.h>

// Problem constants
#define BB   8
#define NN   1024
#define CC   768
#define HH   12
#define DD   64
#define HIDN 3072
#define MROWS 16384   // 2*B*N
#define HALFM 8192

typedef __attribute__((ext_vector_type(8))) short bf16x8;
typedef __attribute__((ext_vector_type(4))) float f32x4;

__device__ __forceinline__ void gload16(const void* g, void* l) {
  __builtin_amdgcn_global_load_lds((const __attribute__((address_space(1))) void*)g,
                                   (__attribute__((address_space(3))) void*)l, 16, 0, 0);
}

__device__ __forceinline__ unsigned short f2bf(float f) {
  __hip_bfloat16 h = __float2bfloat16(f);
  return *reinterpret_cast<unsigned short*>(&h);
}

// ---------------- weight cast f32 -> bf16 (vectorized x4) ----------------
__global__ void cast_f32_bf16(const float* __restrict__ src,
                              unsigned short* __restrict__ dst, int n4) {
  int i = blockIdx.x * blockDim.x + threadIdx.x;
  if (i >= n4) return;
  float4 v = ((const float4*)src)[i];
  ushort4 o;
  o.x = f2bf(v.x); o.y = f2bf(v.y); o.z = f2bf(v.z); o.w = f2bf(v.w);
  ((ushort4*)dst)[i] = o;
}

// ---------------- LayerNorm (f32 in, bf16 out), one block per row ----------------
__global__ __launch_bounds__(256) void ln_kernel(
    const float* __restrict__ src1, const float* __restrict__ src2, int halfRows,
    const float* __restrict__ gam, const float* __restrict__ bet,
    unsigned short* __restrict__ outp) {
  int row = blockIdx.x;
  const float* src = (row < halfRows) ? (src1 + (size_t)row * CC)
                                      : (src2 + (size_t)(row - halfRows) * CC);
  int tid = threadIdx.x;
  float a0 = src[tid], a1 = src[tid + 256], a2 = src[tid + 512];
  float s = a0 + a1 + a2;
  float sq = a0 * a0 + a1 * a1 + a2 * a2;
  __shared__ float sm[8];
  for (int msk = 1; msk < 64; msk <<= 1) {
    s  += __shfl_xor(s, msk);
    sq += __shfl_xor(sq, msk);
  }
  int w = tid >> 6, l = tid & 63;
  if (l == 0) { sm[w] = s; sm[4 + w] = sq; }
  __syncthreads();
  s  = sm[0] + sm[1] + sm[2] + sm[3];
  sq = sm[4] + sm[5] + sm[6] + sm[7];
  float mu  = s * (1.0f / CC);
  float var = sq * (1.0f / CC) - mu * mu;
  float rs  = rsqrtf(var + 1e-5f);
  size_t ob = (size_t)row * CC;
  outp[ob + tid]       = f2bf((a0 - mu) * rs * gam[tid]       + bet[tid]);
  outp[ob + tid + 256] = f2bf((a1 - mu) * rs * gam[tid + 256] + bet[tid + 256]);
  outp[ob + tid + 512] = f2bf((a2 - mu) * rs * gam[tid + 512] + bet[tid + 512]);
}

// ---------------- GEMM: out[M,N] = A[M,K](bf16) @ W[N,K]^T (bf16) ----------------
// EPI 0: bf16 store, no bias (QKV)
// EPI 1: f32 store, + bias + residual (proj, fc2)
// EPI 2: bf16 store, gelu(acc + bias) (fc1)
template <int EPI>
__global__ __launch_bounds__(256) void gemm_bt(
    const unsigned short* __restrict__ A, const unsigned short* __restrict__ W,
    const float* __restrict__ bias,
    const float* __restrict__ res1, const float* __restrict__ res2,
    float* __restrict__ outF, unsigned short* __restrict__ outB,
    int M, int Nn, int K, int halfM) {
  __shared__ unsigned short As[128 * 32];
  __shared__ unsigned short Bs[128 * 32];
  int tid = threadIdx.x;
  int w = tid >> 6, l = tid & 63, lg = l >> 4, li = l & 15;
  int wr = w >> 1, wc = w & 1;
  int tN = blockIdx.x * 128, tM = blockIdx.y * 128;

  f32x4 acc[4][4];
  f32x4 zz = {0.f, 0.f, 0.f, 0.f};
#pragma unroll
  for (int i = 0; i < 4; ++i)
#pragma unroll
    for (int j = 0; j < 4; ++j) acc[i][j] = zz;

  int r4 = tid >> 2;
  int c8 = (tid & 3) * 8;
  const unsigned short* gA0 = A + (size_t)(tM + r4) * K + c8;
  const unsigned short* gA1 = A + (size_t)(tM + 64 + r4) * K + c8;
  const unsigned short* gB0 = W + (size_t)(tN + r4) * K + c8;
  const unsigned short* gB1 = W + (size_t)(tN + 64 + r4) * K + c8;
  unsigned short* lA0 = &As[(size_t)tid * 8];
  unsigned short* lA1 = &As[(size_t)(256 + tid) * 8];
  unsigned short* lB0 = &Bs[(size_t)tid * 8];
  unsigned short* lB1 = &Bs[(size_t)(256 + tid) * 8];

  int nk = K >> 5;
  for (int kt = 0; kt < nk; ++kt) {
    __syncthreads();
    int ko = kt * 32;
    gload16(gA0 + ko, lA0);
    gload16(gA1 + ko, lA1);
    gload16(gB0 + ko, lB0);
    gload16(gB1 + ko, lB1);
    __syncthreads();
    bf16x8 af[4], bq[4];
#pragma unroll
    for (int fm = 0; fm < 4; ++fm)
      af[fm] = *(const bf16x8*)&As[(wr * 64 + fm * 16 + li) * 32 + lg * 8];
#pragma unroll
    for (int fn = 0; fn < 4; ++fn)
      bq[fn] = *(const bf16x8*)&Bs[(wc * 64 + fn * 16 + li) * 32 + lg * 8];
#pragma unroll
    for (int fm = 0; fm < 4; ++fm)
#pragma unroll
      for (int fn = 0; fn < 4; ++fn)
        acc[fm][fn] = __builtin_amdgcn_mfma_f32_16x16x32_bf16(af[fm], bq[fn], acc[fm][fn], 0, 0, 0);
  }

#pragma unroll
  for (int fm = 0; fm < 4; ++fm) {
    int rowb = tM + wr * 64 + fm * 16 + lg * 4;
#pragma unroll
    for (int fn = 0; fn < 4; ++fn) {
      int col = tN + wc * 64 + fn * 16 + li;
      f32x4 v = acc[fm][fn];
#pragma unroll
      for (int rr = 0; rr < 4; ++rr) {
        int row = rowb + rr;
        size_t idx = (size_t)row * Nn + col;
        float x = v[rr];
        if (EPI == 0) {
          outB[idx] = f2bf(x);
        } else if (EPI == 1) {
          float r = (row < halfM) ? res1[(size_t)row * Nn + col]
                                  : res2[(size_t)(row - halfM) * Nn + col];
          outF[idx] = x + bias[col] + r;
        } else {
          float t = x + bias[col];
          float gl = 0.5f * t * (1.0f + erff(t * 0.70710678118654752f));
          outB[idx] = f2bf(gl);
        }
      }
    }
  }
}

// ---------------- Flash attention over qkv buffer ----------------
// qkv: [16384, 2304] bf16 rows: ch0 = rows 0..8191 (from n1), ch1 = 8192.. (from n2)
// Q always from ch0; K/V from channel blockIdx.z. out: [16384, 768] bf16.
//
// LDS layouts (bank-conflict-fixed, r6):
//  Ks [64 kv][8 slot][8]  : slot = (col>>3) ^ (row&7)  (T2 XOR swizzle)
//     staged via global_load_lds with PRE-SWIZZLED global source (linear dest)
//  Vt [64 d ][8 slot][8]  : slot = (kv>>3) ^ (d&7); scatter-write with kv
//     as lane-minor dim -> ~2-way (free) instead of 16-way conflicts
//  Pw [wave][16 q][8 slot][8] : slot = (kv>>3) ^ (q&7)
__global__ __launch_bounds__(256) void attn_kernel(
    const unsigned short* __restrict__ qkv, unsigned short* __restrict__ outp) {
  __shared__ unsigned short Ks[64 * 64];
  __shared__ unsigned short Vt[64 * 64];
  __shared__ unsigned short Pw[4][16 * 64];
  int tid = threadIdx.x;
  int w = tid >> 6, l = tid & 63, lg = l >> 4, li = l & 15;
  int qt = blockIdx.x;
  int b = blockIdx.y / HH;
  int h = blockIdx.y % HH;
  int br = blockIdx.z;

  int qrow0  = b * NN + qt * 64;          // channel 0 rows
  int kvrow0 = br * HALFM + b * NN;
  int orow0  = br * HALFM + b * NN + qt * 64;

  bf16x8 qa[2];
  {
    size_t qr = (size_t)(qrow0 + w * 16 + li) * (3 * CC) + h * DD;
    qa[0] = *(const bf16x8*)(qkv + qr + lg * 8);
    qa[1] = *(const bf16x8*)(qkv + qr + 32 + lg * 8);
  }

  // staging index precompute
  int kr = tid >> 3;        // K: row (0..31), +32 on pass 1
  int ks_slot = tid & 7;    // K: dest slot
  int vkv = tid & 63;       // V: kv (lane-minor -> conflict-free scatter)
  int vwv = tid >> 6;       // V: d-group base (0..3), +4 on pass 1

  float m[4], lsum[4];
  f32x4 oacc[4];
  f32x4 zz = {0.f, 0.f, 0.f, 0.f};
#pragma unroll
  for (int r = 0; r < 4; ++r) { m[r] = -1e30f; lsum[r] = 0.f; }
#pragma unroll
  for (int fn = 0; fn < 4; ++fn) oacc[fn] = zz;

  for (int kt = 0; kt < 16; ++kt) {
    __syncthreads();
    // --- K stage: global_load_lds, linear dest, pre-swizzled source ---
#pragma unroll
    for (int p = 0; p < 2; ++p) {
      int row = kr + p * 32;
      int scol = ((ks_slot ^ (row & 7)) << 3);  // pre-swizzled source col (shorts)
      const unsigned short* src =
          qkv + (size_t)(kvrow0 + kt * 64 + row) * (3 * CC) + CC + h * DD + scol;
      gload16(src, &Ks[(size_t)tid * 8 + p * 2048]);
    }
    // --- V stage: transposed scatter, kv lane-minor ---
#pragma unroll
    for (int p = 0; p < 2; ++p) {
      int dg = vwv + p * 4;  // 0..7
      const unsigned short* src =
          qkv + (size_t)(kvrow0 + kt * 64 + vkv) * (3 * CC) + 2 * CC + h * DD + dg * 8;
      bf16x8 vv = *(const bf16x8*)src;
#pragma unroll
      for (int j = 0; j < 8; ++j) {
        int d = dg * 8 + j;                       // d&7 == j
        Vt[d * 64 + (((vkv >> 3) ^ j) << 3) + (vkv & 7)] = ((unsigned short*)&vv)[j];
      }
    }
    __syncthreads();

    // S = Q K^T (rows: this wave's 16 q-rows; cols: 64 kv)
    f32x4 s[4];
#pragma unroll
    for (int fn = 0; fn < 4; ++fn) s[fn] = zz;
#pragma unroll
    for (int ks = 0; ks < 2; ++ks)
#pragma unroll
      for (int fn = 0; fn < 4; ++fn) {
        int fr = fn * 16 + li;
        bf16x8 bk = *(const bf16x8*)&Ks[fr * 64 + (((ks * 4 + lg) ^ (li & 7)) << 3)];
        s[fn] = __builtin_amdgcn_mfma_f32_16x16x32_bf16(qa[ks], bk, s[fn], 0, 0, 0);
      }
#pragma unroll
    for (int fn = 0; fn < 4; ++fn)
#pragma unroll
      for (int r = 0; r < 4; ++r) s[fn][r] *= 0.125f;

    float p[4][4];
    float alpha[4];
#pragma unroll
    for (int r = 0; r < 4; ++r) {
      float v = fmaxf(fmaxf(s[0][r], s[1][r]), fmaxf(s[2][r], s[3][r]));
      for (int msk = 1; msk < 16; msk <<= 1) v = fmaxf(v, __shfl_xor(v, msk));
      float mn = fmaxf(m[r], v);
      float al = __expf(m[r] - mn);
      m[r] = mn;
      float srow = 0.f;
#pragma unroll
      for (int fn = 0; fn < 4; ++fn) {
        float e = __expf(s[fn][r] - mn);
        p[fn][r] = e;
        srow += e;
      }
      for (int msk = 1; msk < 16; msk <<= 1) srow += __shfl_xor(srow, msk);
      lsum[r] = lsum[r] * al + srow;
      alpha[r] = al;
    }
#pragma unroll
    for (int fn = 0; fn < 4; ++fn)
#pragma unroll
      for (int r = 0; r < 4; ++r) oacc[fn][r] *= alpha[r];

    // P -> per-wave LDS (C-layout -> A-layout reshape), swizzled
#pragma unroll
    for (int fn = 0; fn < 4; ++fn)
#pragma unroll
      for (int r = 0; r < 4; ++r) {
        int q = lg * 4 + r;
        int kvi = fn * 16 + li;
        Pw[w][q * 64 + ((((kvi >> 3)) ^ (q & 7)) << 3) + (li & 7)] = f2bf(p[fn][r]);
      }
    asm volatile("s_waitcnt lgkmcnt(0)" ::: "memory");

    // O += P @ V
#pragma unroll
    for (int ks = 0; ks < 2; ++ks) {
      bf16x8 pa = *(const bf16x8*)&Pw[w][li * 64 + (((ks * 4 + lg) ^ (li & 7)) << 3)];
#pragma unroll
      for (int fn = 0; fn < 4; ++fn) {
        int d = fn * 16 + li;
        bf16x8 bv = *(const bf16x8*)&Vt[d * 64 + (((ks * 4 + lg) ^ (li & 7)) << 3)];
        oacc[fn] = __builtin_amdgcn_mfma_f32_16x16x32_bf16(pa, bv, oacc[fn], 0, 0, 0);
      }
    }
  }

#pragma unroll
  for (int fn = 0; fn < 4; ++fn)
#pragma unroll
    for (int r = 0; r < 4; ++r) {
      int orow = orow0 + w * 16 + lg * 4 + r;
      int ocol = h * DD + fn * 16 + li;
      outp[(size_t)orow * CC + ocol] = f2bf(oacc[fn][r] / lsum[r]);
    }
}

// ---------------- launch ----------------
extern "C" void kernel_launch(void* const* d_in, const int* in_sizes, int n_in,
                              void* d_out, int out_size, void* d_ws, size_t ws_size,
                              hipStream_t stream) {
  const float* x1     = (const float*)d_in[0];
  const float* x2     = (const float*)d_in[1];
  const float* w_qkv  = (const float*)d_in[2];
  const float* w_proj = (const float*)d_in[3];
  const float* b_proj = (const float*)d_in[4];
  const float* g1     = (const float*)d_in[5];
  const float* b1     = (const float*)d_in[6];
  const float* g2     = (const float*)d_in[7];
  const float* b2     = (const float*)d_in[8];
  const float* w_fc1  = (const float*)d_in[9];
  const float* b_fc1  = (const float*)d_in[10];
  const float* w_fc2  = (const float*)d_in[11];
  const float* b_fc2  = (const float*)d_in[12];
  float* out = (float*)d_out;

  char* ws = (char*)d_ws;
  unsigned short* wq   = (unsigned short*)(ws + 0);          //  3,538,944 B
  unsigned short* wp   = (unsigned short*)(ws + 3538944);    //  1,179,648 B
  unsigned short* wf1  = (unsigned short*)(ws + 4718592);    //  4,718,592 B
  unsigned short* wf2  = (unsigned short*)(ws + 9437184);    //  4,718,592 B
  unsigned short* bufA = (unsigned short*)(ws + 14155776);   // 25,165,824 B (n12 / attn_out / ln2)
  unsigned short* bufB = (unsigned short*)(ws + 39321600);   // 100,663,296 B (qkv / mlp hidden)

  // weights -> bf16
  cast_f32_bf16<<<(3 * CC * CC / 4 + 255) / 256, 256, 0, stream>>>(w_qkv, wq, 3 * CC * CC / 4);
  cast_f32_bf16<<<(CC * CC / 4 + 255) / 256, 256, 0, stream>>>(w_proj, wp, CC * CC / 4);
  cast_f32_bf16<<<(HIDN * CC / 4 + 255) / 256, 256, 0, stream>>>(w_fc1, wf1, HIDN * CC / 4);
  cast_f32_bf16<<<(CC * HIDN / 4 + 255) / 256, 256, 0, stream>>>(w_fc2, wf2, CC * HIDN / 4);

  // LN1(x1|x2) -> bufA bf16 [16384,768]
  ln_kernel<<<MROWS, 256, 0, stream>>>(x1, x2, HALFM, g1, b1, bufA);

  // QKV: bufA @ wq^T -> bufB bf16 [16384,2304]
  gemm_bt<0><<<dim3(18, 128), 256, 0, stream>>>(bufA, wq, nullptr, nullptr, nullptr,
                                                nullptr, bufB, MROWS, 3 * CC, CC, HALFM);

  // attention: bufB -> bufA bf16 [16384,768]
  attn_kernel<<<dim3(16, BB * HH, 2), 256, 0, stream>>>(bufB, bufA);

  // proj + bias + residual(x1|x2) -> d_out f32 [16384,768]
  gemm_bt<1><<<dim3(6, 128), 256, 0, stream>>>(bufA, wp, b_proj, x1, x2,
                                               out, nullptr, MROWS, CC, CC, HALFM);

  // LN2(d_out) -> bufA bf16
  ln_kernel<<<MROWS, 256, 0, stream>>>(out, out + (size_t)HALFM * CC, HALFM, g2, b2, bufA);

  // fc1 + bias + gelu -> bufB bf16 [16384,3072]
  gemm_bt<2><<<dim3(24, 128), 256, 0, stream>>>(bufA, wf1, b_fc1, nullptr, nullptr,
                                                nullptr, bufB, MROWS, HIDN, CC, HALFM);

  // fc2 + bias + residual(d_out) -> d_out f32
  gemm_bt<1><<<dim3(6, 128), 256, 0, stream>>>(bufB, wf2, b_fc2, out, out + (size_t)HALFM * CC,
                                               out, nullptr, MROWS, CC, HIDN, HALFM);
}